// Round 9
// baseline (183.450 us; speedup 1.0000x reference)
//
#include <hip/hip_runtime.h>
#include <hip/hip_bf16.h>

// SE3 equivariant cross attention, MI355X gfx950. Round 9.
//  - tail merge: combine+epi+coordfin+memset -> ONE kernel (hatt lives in LDS,
//    dual GEMM from LDS, cscale via shfl+LDS atomics, coords finished in-block).
//  - proj: 64-wide n-tile (4 accs) -> A re-read 8x -> 4x.
//  - prep: cast via LDS 64x64 tiles -> coalesced t8 writes.
//  - attn unchanged from round 8 (anchor).
// Dispatches 7 -> 4.

#define NLIG   1024
#define NPOCK  8192
#define HIDDEN 256
#define ADIM   512
#define NHEAD  4
#define HDIM   64
#define NTAB   1024
#define NSPLIT 16
#define CHUNK  (NPOCK / NSPLIT)   // 512
#define NT     (CHUNK / 32)       // 16
#define LOG2E  1.4426950408889634f
#define QK_SCALE (0.125f * LOG2E)

typedef float f32x16 __attribute__((ext_vector_type(16)));
typedef short short8 __attribute__((ext_vector_type(8)));

union U4S8 { uint4 u; short8 s; };

static __device__ __forceinline__ float exp2h(float x) {
  float r; asm("v_exp_f32 %0, %1" : "=v"(r) : "v"(x)); return r;
}
static __device__ __forceinline__ float rsqh(float x) {
  float r; asm("v_rsq_f32 %0, %1" : "=v"(r) : "v"(x)); return r;
}
static __device__ __forceinline__ unsigned cvtpk(float lo, float hi) {
  unsigned r;
  asm("v_cvt_pk_bf16_f32 %0, %1, %2" : "=v"(r) : "v"(lo), "v"(hi));
  return r;
}
static __device__ __forceinline__ unsigned short f2bf(float f) {
  union { __hip_bfloat16 h; unsigned short u; } c;
  c.h = __float2bfloat16(f);
  return c.u;
}
static __device__ __forceinline__ float bf2f(unsigned u16) {
  union { unsigned uu; float f; } c;
  c.uu = u16 << 16;
  return c.f;
}
static __device__ __forceinline__ short8 load_bf8(const unsigned short* p) {
  U4S8 t; t.u = *(const uint4*)p; return t.s;
}
static __device__ __forceinline__ f32x16 mfma32(short8 a, short8 b, f32x16 c) {
  return __builtin_amdgcn_mfma_f32_32x32x16_bf16(a, b, c, 0, 0, 0);
}
// tile-8 fragment-major layout: 32x8 tiles, row-block major.
static __device__ __forceinline__ size_t t8(int r, int c, int Cdiv8) {
  return ((size_t)((r >> 5) * Cdiv8 + (c >> 3)) << 8) + ((r & 31) << 3) + (c & 7);
}

// ---------------- prep: LDS-tiled casts + weight transposes + edge table ----
#define NCASTA 1024   // h_atomica: 128x8 tiles of 64x64
#define NCASTL 64     // h_lig: 16x4 tiles
#define NTRANS 448
__global__ __launch_bounds__(256)
void prep_kernel(const float* __restrict__ hA, const float* __restrict__ hl,
                 const float* __restrict__ qw, const float* __restrict__ kw,
                 const float* __restrict__ vw, const float* __restrict__ ow,
                 const float* __restrict__ c1w,
                 const float* __restrict__ e1w, const float* __restrict__ e1b,
                 const float* __restrict__ e2w, const float* __restrict__ e2b,
                 unsigned short* __restrict__ hAb, unsigned short* __restrict__ hlb,
                 unsigned short* __restrict__ qwT, unsigned short* __restrict__ kwT,
                 unsigned short* __restrict__ vwT, unsigned short* __restrict__ owT,
                 unsigned short* __restrict__ c1wT, float* __restrict__ tabG) {
  int bx = blockIdx.x;
  int tid = threadIdx.x;
  if (bx < NCASTA + NCASTL) {
    const float* src; unsigned short* dst; int stride, Cdiv8, R0, C0;
    if (bx < NCASTA) {
      src = hA; dst = hAb; stride = ADIM; Cdiv8 = 64;
      R0 = (bx >> 3) * 64; C0 = (bx & 7) * 64;
    } else {
      int b = bx - NCASTA;
      src = hl; dst = hlb; stride = HIDDEN; Cdiv8 = 32;
      R0 = (b >> 2) * 64; C0 = (b & 3) * 64;
    }
    __shared__ float tf[64][65];
    int r = tid >> 2;
#pragma unroll
    for (int pass = 0; pass < 4; ++pass) {
      int c4 = (tid & 3) + pass * 4;
      float4 v = ((const float4*)(src + (size_t)(R0 + r) * stride + C0))[c4];
      tf[r][c4 * 4 + 0] = v.x; tf[r][c4 * 4 + 1] = v.y;
      tf[r][c4 * 4 + 2] = v.z; tf[r][c4 * 4 + 3] = v.w;
    }
    __syncthreads();
    unsigned* dstu = (unsigned*)dst;
    size_t tbase = (size_t)(R0 >> 5) * Cdiv8 + (C0 >> 3);
#pragma unroll
    for (int k = 0; k < 8; ++k) {
      int u = k * 256 + tid;
      int tile = u >> 7, w2 = u & 127;
      int rb = tile >> 3, cb = tile & 7;
      int rr = rb * 32 + (w2 >> 2);
      int c = cb * 8 + (w2 & 3) * 2;
      unsigned val = cvtpk(tf[rr][c], tf[rr][c + 1]);
      dstu[(tbase + (size_t)rb * Cdiv8 + cb) * 128 + w2] = val;
    }
  } else if (bx < NCASTA + NCASTL + NTRANS) {
    int b = bx - (NCASTA + NCASTL);
    const float* src; unsigned short* dst; int K;
    if (b < 64)       { src = qw;  dst = qwT;  K = 256; }
    else if (b < 192) { src = kw;  dst = kwT;  K = 512; b -= 64; }
    else if (b < 320) { src = vw;  dst = vwT;  K = 512; b -= 192; }
    else if (b < 384) { src = ow;  dst = owT;  K = 256; b -= 320; }
    else              { src = c1w; dst = c1wT; K = 256; b -= 384; }
    int kt = K / 32;
    int k0 = (b % kt) * 32, n0 = (b / kt) * 32;
    __shared__ float tile[32][33];
    int tx = tid & 31, ty = tid >> 5;
#pragma unroll
    for (int r = 0; r < 4; ++r)
      tile[ty + 8 * r][tx] = src[(k0 + ty + 8 * r) * 256 + n0 + tx];
    __syncthreads();
#pragma unroll
    for (int r = 0; r < 4; ++r)
      dst[t8(n0 + ty + 8 * r, k0 + tx, K >> 3)] = f2bf(tile[tx][ty + 8 * r]);
  } else {
    int eb = bx - (NCASTA + NCASTL + NTRANS);
    int w = tid >> 6, l = tid & 63;
    int entry = eb * 4 + w;
    float d = (entry + 0.5f) * (10.0f / NTAB);
    float a0 = 0.f, a1 = 0.f, a2 = 0.f, a3 = 0.f;
#pragma unroll
    for (int jj = 0; jj < 4; ++jj) {
      int j = l + jj * 64;
      float v = fmaf(d, e1w[j], e1b[j]);
      float s = v / (1.0f + __expf(-v));
      float4 w2 = ((const float4*)e2w)[j];
      a0 = fmaf(s, w2.x, a0);
      a1 = fmaf(s, w2.y, a1);
      a2 = fmaf(s, w2.z, a2);
      a3 = fmaf(s, w2.w, a3);
    }
#pragma unroll
    for (int m = 32; m >= 1; m >>= 1) {
      a0 += __shfl_xor(a0, m); a1 += __shfl_xor(a1, m);
      a2 += __shfl_xor(a2, m); a3 += __shfl_xor(a3, m);
    }
    if (l == 0) {
      tabG[0 * NTAB + entry] = (a0 + e2b[0]) * LOG2E;
      tabG[1 * NTAB + entry] = (a1 + e2b[1]) * LOG2E;
      tabG[2 * NTAB + entry] = (a2 + e2b[2]) * LOG2E;
      tabG[3 * NTAB + entry] = (a3 + e2b[3]) * LOG2E;
    }
  }
}

// ------------- fused projections, 64-wide n-tile ----------------------------
// grid (72,4): bx<64 -> K/V over NPOCK; bx in [64,72) -> Q over NLIG.
__global__ __launch_bounds__(256)
void proj_kernel(const unsigned short* __restrict__ hAb, const unsigned short* __restrict__ hlb,
                 const unsigned short* __restrict__ kwT, const unsigned short* __restrict__ vwT,
                 const unsigned short* __restrict__ qwT,
                 const float* __restrict__ kb, const float* __restrict__ vb,
                 const float* __restrict__ qb,
                 unsigned short* __restrict__ Kb, unsigned short* __restrict__ VTb,
                 unsigned short* __restrict__ Qb) {
  int tid = threadIdx.x;
  int w = tid >> 6, lane = tid & 63;
  int lo = lane & 31, hi = lane >> 5;
  int n0 = blockIdx.y * 64;
  if (blockIdx.x < 64) {
    int m0 = blockIdx.x * 128 + w * 32;
    const unsigned short* ap   = hAb + t8(m0 + lo, hi * 8, 64);
    const unsigned short* bk0p = kwT + t8(n0 + lo, hi * 8, 64);
    const unsigned short* bk1p = bk0p + 64 * 256;                 // +32 rows
    const unsigned short* bv0p = vwT + t8(n0 + lo, hi * 8, 64);
    const unsigned short* bv1p = bv0p + 64 * 256;
    f32x16 aK0, aK1, aV0, aV1;
#pragma unroll
    for (int i = 0; i < 16; ++i) { aK0[i] = 0.f; aK1[i] = 0.f; aV0[i] = 0.f; aV1[i] = 0.f; }
#pragma unroll 4
    for (int kk = 0; kk < ADIM / 16; ++kk) {
      short8 a   = load_bf8(ap + kk * 512);
      short8 bk0 = load_bf8(bk0p + kk * 512);
      short8 bk1 = load_bf8(bk1p + kk * 512);
      short8 bv0 = load_bf8(bv0p + kk * 512);
      short8 bv1 = load_bf8(bv1p + kk * 512);
      aK0 = mfma32(a, bk0, aK0);
      aK1 = mfma32(a, bk1, aK1);
      aV0 = mfma32(bv0, a, aV0);     // swapped -> C[n][m]
      aV1 = mfma32(bv1, a, aV1);
    }
    float bnK0 = kb[n0 + lo], bnK1 = kb[n0 + 32 + lo];
#pragma unroll
    for (int g = 0; g < 4; ++g) {
#pragma unroll
      for (int rr = 0; rr < 4; ++rr) {
        int r = g * 4 + rr;
        int row = g * 8 + hi * 4 + rr;
        Kb[t8(m0 + row, n0 + lo, 32)]      = f2bf(aK0[r] + bnK0);
        Kb[t8(m0 + row, n0 + 32 + lo, 32)] = f2bf(aK1[r] + bnK1);
        VTb[t8(n0 + row, m0 + lo, 1024)]      = f2bf(aV0[r] + vb[n0 + row]);
        VTb[t8(n0 + 32 + row, m0 + lo, 1024)] = f2bf(aV1[r] + vb[n0 + 32 + row]);
      }
    }
  } else {
    int m0 = (blockIdx.x - 64) * 128 + w * 32;
    const unsigned short* ap  = hlb + t8(m0 + lo, hi * 8, 32);
    const unsigned short* b0p = qwT + t8(n0 + lo, hi * 8, 32);
    const unsigned short* b1p = b0p + 32 * 256;
    f32x16 a0, a1;
#pragma unroll
    for (int i = 0; i < 16; ++i) { a0[i] = 0.f; a1[i] = 0.f; }
#pragma unroll 8
    for (int kk = 0; kk < HIDDEN / 16; ++kk) {
      short8 a  = load_bf8(ap + kk * 512);
      short8 b0 = load_bf8(b0p + kk * 512);
      short8 b1 = load_bf8(b1p + kk * 512);
      a0 = mfma32(a, b0, a0);
      a1 = mfma32(a, b1, a1);
    }
    float bn0 = qb[n0 + lo], bn1 = qb[n0 + 32 + lo];
#pragma unroll
    for (int g = 0; g < 4; ++g) {
#pragma unroll
      for (int rr = 0; rr < 4; ++rr) {
        int r = g * 4 + rr;
        int m = m0 + g * 8 + hi * 4 + rr;
        Qb[t8(m, n0 + lo, 32)]      = f2bf(a0[r] + bn0);
        Qb[t8(m, n0 + 32 + lo, 32)] = f2bf(a1[r] + bn1);
      }
    }
  }
}

// ------------- flash cross-attention with geometry (unchanged r8) -----------
__global__ __launch_bounds__(256)
void attn_kernel(const unsigned short* __restrict__ Qbf, const unsigned short* __restrict__ Kbf,
                 const unsigned short* __restrict__ VTbf,
                 const float* __restrict__ x_lig, const float* __restrict__ x_pocket,
                 const float* __restrict__ tabG,
                 unsigned* __restrict__ partOb, float4* __restrict__ partZC) {
  __shared__ float4 xch[CHUNK];            // 8 KB
  __shared__ float tab[NHEAD][NTAB];       // 16 KB

  int tid = threadIdx.x;
  int h = tid >> 6;
  int lane = tid & 63;
  int lo = lane & 31, hi = lane >> 5;
  int qt = blockIdx.x & 31;
  int split = blockIdx.x >> 5;
  int q0 = qt * 32;
  int j0g = split * CHUNK;

  for (int i = tid; i < CHUNK; i += 256) {
    float x = x_pocket[(j0g + i) * 3 + 0];
    float y = x_pocket[(j0g + i) * 3 + 1];
    float z = x_pocket[(j0g + i) * 3 + 2];
    float4 v; v.x = x; v.y = y; v.z = z; v.w = 0.f;
    xch[i] = v;
  }
  for (int i = tid; i < NHEAD * NTAB; i += 256) ((float*)tab)[i] = tabG[i];
  __syncthreads();

  int q = q0 + lo;
  float xl0 = x_lig[q * 3 + 0];
  float xl1 = x_lig[q * 3 + 1];
  float xl2 = x_lig[q * 3 + 2];

  short8 qfr[4];
#pragma unroll
  for (int kk = 0; kk < 4; ++kk)
    qfr[kk] = load_bf8(Qbf + t8(q, h * HDIM + kk * 16 + hi * 8, 32));

  const unsigned short* kbp = Kbf + t8(j0g + lo, h * HDIM + hi * 8, 32);
  const unsigned short* vbp = VTbf + t8(h * HDIM + lo, j0g + hi * 8, 1024);

  f32x16 O0, O1;
#pragma unroll
  for (int i = 0; i < 16; ++i) { O0[i] = 0.f; O1[i] = 0.f; }
  float Z = 0.f, c0 = 0.f, c1 = 0.f, c2 = 0.f;

  short8 kcur[4];
#pragma unroll
  for (int kk = 0; kk < 4; ++kk) kcur[kk] = load_bf8(kbp + kk * 512);

#pragma unroll 1
  for (int t = 0; t < NT; ++t) {
    int jb = t * 32;
    int tn = (t + 1 < NT) ? (t + 1) : t;
    short8 knx0 = load_bf8(kbp + (size_t)tn * 8192 + 0 * 512);
    short8 knx1 = load_bf8(kbp + (size_t)tn * 8192 + 1 * 512);
    short8 knx2 = load_bf8(kbp + (size_t)tn * 8192 + 2 * 512);
    short8 knx3 = load_bf8(kbp + (size_t)tn * 8192 + 3 * 512);
    short8 v00 = load_bf8(vbp + (size_t)t * 1024);
    short8 v01 = load_bf8(vbp + (size_t)t * 1024 + 262144);
    short8 v10 = load_bf8(vbp + (size_t)t * 1024 + 512);
    short8 v11 = load_bf8(vbp + (size_t)t * 1024 + 512 + 262144);

    f32x16 s;
#pragma unroll
    for (int i = 0; i < 16; ++i) s[i] = 0.f;
    s = mfma32(kcur[0], qfr[0], s);
    s = mfma32(kcur[1], qfr[1], s);
    s = mfma32(kcur[2], qfr[2], s);
    s = mfma32(kcur[3], qfr[3], s);

    unsigned wp[8];
    float pprev = 0.f;
#pragma unroll
    for (int r = 0; r < 16; ++r) {
      int jl = (r & 3) + 8 * (r >> 2) + 4 * hi;
      float4 xp = xch[jb + jl];
      float dx = xp.x - xl0, dy = xp.y - xl1, dz = xp.z - xl2;
      float r2 = fmaf(dx, dx, fmaf(dy, dy, dz * dz));
      float r2c = fmaxf(r2, 1e-24f);
      float rinv = rsqh(r2c);
      float d = r2c * rinv;
      int idx = (int)(d * (NTAB / 10.0f));
      idx = idx > (NTAB - 1) ? (NTAB - 1) : idx;
      float b = tab[h][idx];
      float s2 = fmaf(s[r], QK_SCALE, b);
      float pe = (r2 < 100.0f) ? exp2h(s2) : 0.0f;
      Z += pe;
      float pr = pe * rinv;
      c0 = fmaf(pr, dx, c0);
      c1 = fmaf(pr, dy, c1);
      c2 = fmaf(pr, dz, c2);
      if (r & 1) wp[r >> 1] = cvtpk(pprev, pe); else pprev = pe;
    }
    {
      unsigned W0 = wp[0], W1 = wp[1], W2 = wp[2], W3 = wp[3];
      unsigned e01 = (unsigned)__shfl_xor((int)(hi ? W0 : W2), 32);
      unsigned e23 = (unsigned)__shfl_xor((int)(hi ? W1 : W3), 32);
      U4S8 pb;
      pb.u.x = hi ? e01 : W0;
      pb.u.y = hi ? e23 : W1;
      pb.u.z = hi ? W2 : e01;
      pb.u.w = hi ? W3 : e23;
      O0 = mfma32(v00, pb.s, O0);
      O1 = mfma32(v01, pb.s, O1);
    }
    {
      unsigned W0 = wp[4], W1 = wp[5], W2 = wp[6], W3 = wp[7];
      unsigned e01 = (unsigned)__shfl_xor((int)(hi ? W0 : W2), 32);
      unsigned e23 = (unsigned)__shfl_xor((int)(hi ? W1 : W3), 32);
      U4S8 pb;
      pb.u.x = hi ? e01 : W0;
      pb.u.y = hi ? e23 : W1;
      pb.u.z = hi ? W2 : e01;
      pb.u.w = hi ? W3 : e23;
      O0 = mfma32(v10, pb.s, O0);
      O1 = mfma32(v11, pb.s, O1);
    }
    kcur[0] = knx0; kcur[1] = knx1; kcur[2] = knx2; kcur[3] = knx3;
  }

  unsigned* po = partOb + ((size_t)(split * NLIG + q) * (HIDDEN / 2)) + h * (HDIM / 2);
#pragma unroll
  for (int g = 0; g < 4; ++g) {
    uint2 u0;
    u0.x = cvtpk(O0[g * 4 + 0], O0[g * 4 + 1]);
    u0.y = cvtpk(O0[g * 4 + 2], O0[g * 4 + 3]);
    *(uint2*)(po + g * 4 + hi * 2) = u0;
    uint2 u1;
    u1.x = cvtpk(O1[g * 4 + 0], O1[g * 4 + 1]);
    u1.y = cvtpk(O1[g * 4 + 2], O1[g * 4 + 3]);
    *(uint2*)(po + 16 + g * 4 + hi * 2) = u1;
  }
  float Zt = Z + __shfl_xor(Z, 32);
  float c0t = c0 + __shfl_xor(c0, 32);
  float c1t = c1 + __shfl_xor(c1, 32);
  float c2t = c2 + __shfl_xor(c2, 32);
  if (hi == 0) {
    float4 zc; zc.x = Zt; zc.y = c0t; zc.z = c1t; zc.w = c2t;
    partZC[(size_t)(split * NLIG + q) * NHEAD + h] = zc;
  }
}

// ------------- tail: combine + dual epilogue GEMM + coord update ------------
// grid 32 blocks x 512 threads (8 waves). Per block: 32 q rows.
__global__ __launch_bounds__(512)
void tail_kernel(const unsigned* __restrict__ partOb, const float4* __restrict__ partZC,
                 const unsigned short* __restrict__ owT, const unsigned short* __restrict__ c1wT,
                 const float* __restrict__ ob, const float* __restrict__ c1b,
                 const float* __restrict__ c2w, const float* __restrict__ c2b,
                 const float* __restrict__ h_lig, const float* __restrict__ x_lig,
                 float* __restrict__ hout, float* __restrict__ xout) {
  __shared__ unsigned hattL[32 * 128];   // 32q x 256c bf16, t8 (single row-block): 16KB
  __shared__ float invL[32][4];
  __shared__ float cmsgL[32][3];
  __shared__ float cscL[32];

  int t = threadIdx.x;
  int q0 = blockIdx.x * 32;

  // phase A1: Z / coord sums per (q,h)
  if (t < 128) {
    int i = t >> 2, h = t & 3;
    float zz = 0.f, a0 = 0.f, a1 = 0.f, a2 = 0.f;
#pragma unroll
    for (int s = 0; s < NSPLIT; ++s) {
      float4 v = partZC[(size_t)(s * NLIG + q0 + i) * NHEAD + h];
      zz += v.x; a0 += v.y; a1 += v.z; a2 += v.w;
    }
    invL[i][h] = (zz > 0.f) ? 1.0f / zz : 0.f;
    float iv = (zz > 0.f) ? 0.25f / zz : 0.f;
    a0 *= iv; a1 *= iv; a2 *= iv;
    a0 += __shfl_xor(a0, 1); a0 += __shfl_xor(a0, 2);
    a1 += __shfl_xor(a1, 1); a1 += __shfl_xor(a1, 2);
    a2 += __shfl_xor(a2, 1); a2 += __shfl_xor(a2, 2);
    if (h == 0) { cmsgL[i][0] = a0; cmsgL[i][1] = a1; cmsgL[i][2] = a2; }
  }
  if (t < 32) cscL[t] = 0.f;
  __syncthreads();

  // phase A2: combine O partials -> hattL (t8 bf16)
  {
    int c2i = t & 127;
    int c = c2i * 2;
#pragma unroll
    for (int i = t >> 7; i < 32; i += 4) {
      float o0 = 0.f, o1 = 0.f;
#pragma unroll
      for (int s = 0; s < NSPLIT; ++s) {
        unsigned u = partOb[(size_t)(s * NLIG + q0 + i) * 128 + c2i];
        o0 += bf2f(u & 0xffffu);
        o1 += bf2f(u >> 16);
      }
      float inv = invL[i][c >> 6];
      hattL[(c >> 3) * 128 + i * 4 + ((c & 7) >> 1)] = cvtpk(o0 * inv, o1 * inv);
    }
  }
  __syncthreads();

  // phase B: dual GEMM (32 x 256) @ (256 x 256) for ow and c1w
  int w = t >> 6, lane = t & 63;
  int lo = lane & 31, hi = lane >> 5;
  int n = w * 32 + lo;
  const unsigned short* bo = owT + t8(n, hi * 8, 32);
  const unsigned short* bc = c1wT + t8(n, hi * 8, 32);
  f32x16 aO, aC;
#pragma unroll
  for (int i = 0; i < 16; ++i) { aO[i] = 0.f; aC[i] = 0.f; }
#pragma unroll 8
  for (int kk = 0; kk < 16; ++kk) {
    U4S8 av; av.u = *(const uint4*)&hattL[(kk * 2 + hi) * 128 + lo * 4];
    short8 b1 = load_bf8(bo + kk * 512);
    short8 b2 = load_bf8(bc + kk * 512);
    aO = mfma32(av.s, b1, aO);
    aC = mfma32(av.s, b2, aC);
  }
  float obn = ob[n], c1bn = c1b[n], c2wn = c2w[n];
#pragma unroll
  for (int g = 0; g < 4; ++g) {
#pragma unroll
    for (int rr = 0; rr < 4; ++rr) {
      int r = g * 4 + rr;
      int mi = g * 8 + hi * 4 + rr;
      int m = q0 + mi;
      hout[(size_t)m * HIDDEN + n] = aO[r] + obn + h_lig[(size_t)m * HIDDEN + n];
      float v = aC[r] + c1bn;
      float sg = v / (1.0f + exp2h(-LOG2E * v));
      float part = sg * c2wn;
#pragma unroll
      for (int msk = 16; msk >= 1; msk >>= 1) part += __shfl_xor(part, msk);
      if (lo == 0) atomicAdd(&cscL[mi], part);
    }
  }
  __syncthreads();

  // phase C: coordinate update
  if (t < 96) {
    int i = t / 3, d = t % 3;
    int q = q0 + i;
    xout[q * 3 + d] = x_lig[q * 3 + d] + (cscL[i] + c2b[0]) * cmsgL[i][d];
  }
}

extern "C" void kernel_launch(void* const* d_in, const int* in_sizes, int n_in,
                              void* d_out, int out_size, void* d_ws, size_t ws_size,
                              hipStream_t stream) {
  const float* h_lig  = (const float*)d_in[0];
  const float* x_lig  = (const float*)d_in[1];
  const float* h_atom = (const float*)d_in[2];
  const float* x_pock = (const float*)d_in[3];
  const float* qw  = (const float*)d_in[4];
  const float* qb  = (const float*)d_in[5];
  const float* kw  = (const float*)d_in[6];
  const float* kb  = (const float*)d_in[7];
  const float* vw  = (const float*)d_in[8];
  const float* vb  = (const float*)d_in[9];
  const float* ow  = (const float*)d_in[10];
  const float* ob  = (const float*)d_in[11];
  const float* e1w = (const float*)d_in[12];
  const float* e1b = (const float*)d_in[13];
  const float* e2w = (const float*)d_in[14];
  const float* e2b = (const float*)d_in[15];
  const float* c1w = (const float*)d_in[16];
  const float* c1b = (const float*)d_in[17];
  const float* c2w = (const float*)d_in[18];
  const float* c2b = (const float*)d_in[19];

  char* w = (char*)d_ws;
  unsigned short* hAb  = (unsigned short*)w; w += (size_t)NPOCK * ADIM * 2;
  unsigned short* hlb  = (unsigned short*)w; w += (size_t)NLIG * HIDDEN * 2;
  unsigned short* qwT  = (unsigned short*)w; w += 256 * 256 * 2;
  unsigned short* kwT  = (unsigned short*)w; w += 256 * 512 * 2;
  unsigned short* vwT  = (unsigned short*)w; w += 256 * 512 * 2;
  unsigned short* owT  = (unsigned short*)w; w += 256 * 256 * 2;
  unsigned short* c1wT = (unsigned short*)w; w += 256 * 256 * 2;
  unsigned short* Qb   = (unsigned short*)w; w += (size_t)NLIG * HIDDEN * 2;
  unsigned short* Kb   = (unsigned short*)w; w += (size_t)NPOCK * HIDDEN * 2;
  unsigned short* VTb  = (unsigned short*)w; w += (size_t)HIDDEN * NPOCK * 2;
  float* tabG          = (float*)w;          w += NHEAD * NTAB * 4;
  unsigned* partOb     = (unsigned*)w;       w += (size_t)NSPLIT * NLIG * HIDDEN * 2;
  float* partZC        = (float*)w;          w += (size_t)NSPLIT * NLIG * NHEAD * 4 * 4;

  float* hout = (float*)d_out;
  float* xout = ((float*)d_out) + (size_t)NLIG * HIDDEN;

  prep_kernel<<<NCASTA + NCASTL + NTRANS + NTAB / 4, 256, 0, stream>>>(
      h_atom, h_lig, qw, kw, vw, ow, c1w, e1w, e1b, e2w, e2b,
      hAb, hlb, qwT, kwT, vwT, owT, c1wT, tabG);
  proj_kernel<<<dim3(72, 4), 256, 0, stream>>>(
      hAb, hlb, kwT, vwT, qwT, kb, vb, qb, Kb, VTb, Qb);
  attn_kernel<<<32 * NSPLIT, 256, 0, stream>>>(Qb, Kb, VTb, x_lig, x_pock, tabG,
                                               partOb, (float4*)partZC);
  tail_kernel<<<32, 512, 0, stream>>>(partOb, (const float4*)partZC, owT, c1wT,
                                      ob, c1b, c2w, c2b, h_lig, x_lig, hout, xout);
}